// Round 1
// 246.136 us; speedup vs baseline: 1.0060x; 1.0060x over previous
//
#include <hip/hip_runtime.h>
#include <math.h>

// Problem constants
#define NS    8000      // N samples
#define TT    64        // T
#define FF    64        // F
#define EE    8         // E
#define WIN   40        // WINDOW
#define TR    59        // rows of xe kept: t = 5..63
#define NBINS 4096

// ws layout (floats):
//   xeT  [8][59][8000]  = 3,776,000
//   rankT[8][40][8000]  = 2,560,000
//   uraw [8000][40][5]  = 1,600,000
#define XET_SZ  (8*59*8000)
#define RNK_SZ  (8*40*8000)

// ---------------------------------------------------------------------------
// K0: fused transpose + raw-channel conv fold (unchanged).
// ---------------------------------------------------------------------------
__global__ __launch_bounds__(256) void k0(const float* __restrict__ x,
                                          const float* __restrict__ cw,
                                          float* __restrict__ xeT,
                                          float* __restrict__ uraw) {
    int n = blockIdx.x * 256 + threadIdx.x;
    int r = blockIdx.y;              // 0..58
    if (n >= NS) return;
    const float* row = x + (size_t)n * (TT * FF) + (5 + r) * FF;
    float4 a = *(const float4*)(row);
    float4 b = *(const float4*)(row + 4);
    xeT[(0 * TR + r) * NS + n] = a.x;
    xeT[(1 * TR + r) * NS + n] = a.y;
    xeT[(2 * TR + r) * NS + n] = a.z;
    xeT[(3 * TR + r) * NS + n] = a.w;
    xeT[(4 * TR + r) * NS + n] = b.x;
    xeT[(5 * TR + r) * NS + n] = b.y;
    xeT[(6 * TR + r) * NS + n] = b.z;
    xeT[(7 * TR + r) * NS + n] = b.w;

    if (r >= 19) {                   // t = 24+w, w = r-19
        const int w = r - 19;
        const float* W = cw + 127 * 144 * 5;
        float4 v[16];
        v[0] = a; v[1] = b;
#pragma unroll
        for (int q = 2; q < 16; q++) v[q] = *(const float4*)(row + 4 * q);
        float acc0 = 0.f, acc1 = 0.f, acc2 = 0.f, acc3 = 0.f, acc4 = 0.f;
#pragma unroll
        for (int q = 0; q < 16; q++) {
            const float* Wq = W + (4 * q) * 5;   // uniform -> s_load
            acc0 += v[q].x * Wq[0]  + v[q].y * Wq[5]  + v[q].z * Wq[10] + v[q].w * Wq[15];
            acc1 += v[q].x * Wq[1]  + v[q].y * Wq[6]  + v[q].z * Wq[11] + v[q].w * Wq[16];
            acc2 += v[q].x * Wq[2]  + v[q].y * Wq[7]  + v[q].z * Wq[12] + v[q].w * Wq[17];
            acc3 += v[q].x * Wq[3]  + v[q].y * Wq[8]  + v[q].z * Wq[13] + v[q].w * Wq[18];
            acc4 += v[q].x * Wq[4]  + v[q].y * Wq[9]  + v[q].z * Wq[14] + v[q].w * Wq[19];
        }
        float* o = uraw + ((size_t)n * WIN + w) * 5;
        o[0] = acc0; o[1] = acc1; o[2] = acc2; o[3] = acc3; o[4] = acc4;
    }
}

// ---------------------------------------------------------------------------
// KR v4: exact cross-batch descending rank, 2 blocks/CU.
// Single hist[NBINS+1] array serves as histogram -> suffix cursor -> bucket
// bounds: post-scatter, hist[b] = end of bucket b, hist[b+1] = start.
// 4096 bins over [-4,4] (avg bucket ~6). LDS = 16.4K hist + 64K keys
// = 80.5 KB -> 2 blocks/CU, all 320 blocks resident in ONE round (v3 was
// 129.6 KB -> 1 block/CU -> 2-round quantization at 62.5% util).
// ---------------------------------------------------------------------------
__device__ __forceinline__ int binOf(float v) {
    int b = (int)((v + 4.0f) * 512.0f);    // monotone; clamped
    b = b < 0 ? 0 : b;
    return b > (NBINS - 1) ? (NBINS - 1) : b;
}

__device__ __forceinline__ unsigned long long keyOf(float v, unsigned idx) {
    unsigned s = __float_as_uint(v);
    unsigned m = (s & 0x80000000u) ? (~s) : (s | 0x80000000u); // ascending mono
    unsigned md = ~m;                                          // descending
    return ((unsigned long long)md << 13) | idx;
}

__global__ __launch_bounds__(1024) void k_rank(const float* __restrict__ xeT,
                                               float* __restrict__ rankT) {
    const int w = blockIdx.x;   // 0..39
    const int e = blockIdx.y;   // 0..7
    __shared__ unsigned hist[NBINS + 1];         // hist -> cursor -> bounds
    __shared__ unsigned long long sk[NS];        // bucket-grouped keys
    __shared__ unsigned wsum[16];

    const int tid  = threadIdx.x;
    const int lane = tid & 63;
    const int wid  = tid >> 6;
    const float* col = xeT + ((size_t)e * TR + (19 + w)) * NS;   // t = 24+w

    float val[8];
#pragma unroll
    for (int i = 0; i < 8; i++) {
        int idx = tid + i * 1024;
        val[i] = (idx < NS) ? col[idx] : 0.0f;
    }
#pragma unroll
    for (int j = 0; j < 4; j++) hist[tid + j * 1024] = 0;
    if (tid == 0) hist[NBINS] = 0;               // never touched again
    __syncthreads();

#pragma unroll
    for (int i = 0; i < 8; i++) {
        int idx = tid + i * 1024;
        if (idx < NS) atomicAdd(&hist[binOf(val[i])], 1u);
    }
    __syncthreads();

    // suffix offsets: 4 bins/thread; wave scan + cross-wave offsets
    unsigned h[4];
#pragma unroll
    for (int j = 0; j < 4; j++) h[j] = hist[4 * tid + j];
    unsigned cs = h[0] + h[1] + h[2] + h[3];
    unsigned sc = cs;
#pragma unroll
    for (int d = 1; d < 64; d <<= 1) {
        unsigned t2 = __shfl_up(sc, d);
        if (lane >= d) sc += t2;
    }
    if (lane == 63) wsum[wid] = sc;
    __syncthreads();
    unsigned woff = 0;
    for (int i = 0; i < wid; i++) woff += wsum[i];
    unsigned bsum = woff + (sc - cs);   // # elements in bins < 4*tid
#pragma unroll
    for (int j = 0; j < 4; j++) {
        int b = 4 * tid + j;
        hist[b] = NS - bsum - h[j];     // scatter cursor = bucket start
        bsum += h[j];
    }
    __syncthreads();

    // scatter keys into bucket-grouped order (descending-bucket layout)
#pragma unroll
    for (int i = 0; i < 8; i++) {
        int idx = tid + i * 1024;
        if (idx < NS) {
            int b = binOf(val[i]);
            unsigned p = atomicAdd(&hist[b], 1u);
            sk[p] = keyOf(val[i], (unsigned)idx);
        }
    }
    __syncthreads();

    // exact rank: post-scatter hist[b] = bucket-b end, hist[b+1] = start.
    float* outp = rankT + ((size_t)e * WIN + w) * NS;
#pragma unroll 1
    for (int i = 0; i < 8; i++) {
        int p = tid + i * 1024;
        if (p < NS) {
            unsigned long long k64 = sk[p];
            // recover value bit-exactly from key to re-derive the bin
            unsigned md = (unsigned)(k64 >> 13);
            unsigned m  = ~md;
            unsigned s  = (m & 0x80000000u) ? (m ^ 0x80000000u) : (~m);
            float v = __uint_as_float(s);
            int b = binOf(v);
            unsigned lo = hist[b + 1];           // = old basev[b]
            unsigned hi = hist[b];               // = old bend[b]
            unsigned c = 0;
            for (unsigned q = lo; q < hi; q++) c += (sk[q] < k64);
            outp[k64 & 8191u] = (float)(lo + c) * (1.0f / 8000.0f);
        }
    }
}

// ---------------------------------------------------------------------------
// KDF v2: derived-stats + conv-fold + epilogue, window loop split 4-ways.
// Thread = (n, e, quarter); quarter q owns windows w in [10q, 10q+10), ring
// over 29 xeT rows. 500 blocks x 512 threads = 4000 waves (~4/SIMD) vs the
// old 1000 waves (~1/SIMD, latency-exposed). gl[14] local accumulator slots
// map j = w-k via lq = j - 10q + 4. LDS: red[32][16][15] + fin[16][37]
// = 33 KB; 16 threads do the leaky+dot epilogue per block.
// ---------------------------------------------------------------------------
__global__ __launch_bounds__(512) void k_der_final(const float* __restrict__ cw,
                                                   const float* __restrict__ xeT,
                                                   const float* __restrict__ rankT,
                                                   const float* __restrict__ uraw,
                                                   const float* __restrict__ cb,
                                                   const float* __restrict__ lw,
                                                   const float* __restrict__ lb,
                                                   float* __restrict__ outp) {
    __shared__ float red[32][16][15];
    __shared__ float fin[16][37];
    const int tid = threadIdx.x;
    const int nl  = tid & 15;          // 0..15
    const int e   = (tid >> 4) & 7;    // 0..7
    const int q4  = tid >> 7;          // 0..3
    const int g   = tid >> 4;          // 0..31 == q4*8 + e
    const int n0  = blockIdx.x * 16;   // 500 blocks * 16 = 8000
    const int n   = n0 + nl;
    const int w0  = q4 * 10;
    const float* W = cw + 127 * 144 * 5;

    // preload this e's 45 weights (rank folds two channels)
    float wm5[5], wsd5[5], wrk[5], wmx5[5], wmn5[5], wm20[5], wsd20[5], wmx20[5], wmn20[5];
#pragma unroll
    for (int k = 0; k < 5; k++) {
        wm5[k]   = W[(64  + e) * 5 + k];
        wsd5[k]  = W[(72  + e) * 5 + k];
        wrk[k]   = W[(80  + e) * 5 + k] + W[(120 + e) * 5 + k];
        wmx5[k]  = W[(88  + e) * 5 + k];
        wmn5[k]  = W[(96  + e) * 5 + k];
        wm20[k]  = W[(104 + e) * 5 + k];
        wsd20[k] = W[(112 + e) * 5 + k];
        wmx20[k] = W[(128 + e) * 5 + k];
        wmn20[k] = W[(136 + e) * 5 + k];
    }

    float gl[14];
#pragma unroll
    for (int j = 0; j < 14; j++) gl[j] = 0.0f;

    const float* col = xeT + ((size_t)e * TR + w0) * NS + n;
    const float* rkp = rankT + ((size_t)e * WIN + w0) * NS + n;

    float ring[20];
#pragma unroll
    for (int r = 0; r < 19; r++) ring[r] = col[(size_t)r * NS];

#pragma unroll
    for (int i = 0; i < 10; i++) {     // window w = w0 + i
        ring[(i + 19) % 20] = col[(size_t)(i + 19) * NS];
        // month window = rows (w0+i)..(w0+i+19): all 20 ring slots
        float s20 = 0.f, mn20 = ring[0], mx20 = ring[0];
#pragma unroll
        for (int t = 0; t < 20; t++) {
            float v = ring[t];
            s20 += v; mn20 = fminf(mn20, v); mx20 = fmaxf(mx20, v);
        }
        float m20 = s20 * (1.0f / 20.0f);
        float d20 = 0.f;
#pragma unroll
        for (int t = 0; t < 20; t++) { float d = ring[t] - m20; d20 += d * d; }
        float sd20 = sqrtf(d20 * (1.0f / 19.0f));

        // week window = last 5 rows
        float s5 = 0.f, mn5 = ring[(i + 15) % 20], mx5 = mn5;
#pragma unroll
        for (int t = 15; t < 20; t++) {
            float v = ring[(i + t) % 20];
            s5 += v; mn5 = fminf(mn5, v); mx5 = fmaxf(mx5, v);
        }
        float m5 = s5 * 0.2f;
        float d5 = 0.f;
#pragma unroll
        for (int t = 15; t < 20; t++) {
            float d = ring[(i + t) % 20] - m5; d5 += d * d;
        }
        float sd5 = sqrtf(d5 * 0.25f);

        float rk = rkp[(size_t)i * NS];

#pragma unroll
        for (int k = 0; k < 5; k++) {
            int j = w0 + i - k;
            if (j >= 0 && j < 36) {
                float uk;
                uk  = m5   * wm5[k];
                uk += sd5  * wsd5[k];
                uk += rk   * wrk[k];
                uk += mx5  * wmx5[k];
                uk += mn5  * wmn5[k];
                uk += m20  * wm20[k];
                uk += sd20 * wsd20[k];
                uk += mx20 * wmx20[k];
                uk += mn20 * wmn20[k];
                gl[i - k + 4] += uk;   // static index after unroll
            }
        }
    }

    // stage partials: red[g][nl][lq]; stride 15 words -> conflict-free
#pragma unroll
    for (int jj = 0; jj < 14; jj++) red[g][nl][jj] = gl[jj];
    __syncthreads();

    // reduce over (quarter, e): fin[nl2][j] = sum of mapped slots
    for (int p = tid; p < 16 * 36; p += 512) {
        int nl2 = p / 36, j = p - nl2 * 36;
        float s = 0.f;
#pragma unroll
        for (int qq = 0; qq < 4; qq++) {
            int lq = j - 10 * qq + 4;
            if (lq >= 0 && lq < 14) {
#pragma unroll
                for (int e2 = 0; e2 < 8; e2++) s += red[qq * 8 + e2][nl2][lq];
            }
        }
        fin[nl2][j] = s;
    }
    __syncthreads();

    // epilogue: 16 threads, one n each
    if (tid < 16) {
        const float* ur = uraw + (size_t)n * (WIN * 5);
        float b127 = cb[127];
        float acc = lb[0];
#pragma unroll
        for (int j = 0; j < 36; j++) {
            float gsum = b127 + fin[tid][j];
#pragma unroll
            for (int k = 0; k < 5; k++) gsum += ur[(j + k) * 5 + k];
            gsum = (gsum >= 0.0f) ? gsum : 0.01f * gsum;
            acc += gsum * lw[j];
        }
        outp[n] = acc;
    }
}

// ---------------------------------------------------------------------------
extern "C" void kernel_launch(void* const* d_in, const int* in_sizes, int n_in,
                              void* d_out, int out_size, void* d_ws, size_t ws_size,
                              hipStream_t stream) {
    const float* x  = (const float*)d_in[0];   // [8000,64,64]
    const float* cw = (const float*)d_in[1];   // [128,144,5]
    const float* cb = (const float*)d_in[2];   // [128]
    const float* lw = (const float*)d_in[3];   // [1,36]
    const float* lb = (const float*)d_in[4];   // [1]
    float* outp = (float*)d_out;               // [8000,1]

    float* ws    = (float*)d_ws;
    float* xeT   = ws;                         // 8*59*8000
    float* rankT = ws + XET_SZ;                // 8*40*8000
    float* uraw  = ws + XET_SZ + RNK_SZ;       // 8000*40*5

    k0<<<dim3(32, 59), 256, 0, stream>>>(x, cw, xeT, uraw);
    k_rank<<<dim3(WIN, EE), 1024, 0, stream>>>(xeT, rankT);
    k_der_final<<<500, 512, 0, stream>>>(cw, xeT, rankT, uraw, cb, lw, lb, outp);
}